// Round 1
// baseline (77.644 us; speedup 1.0000x reference)
//
#include <hip/hip_runtime.h>
#include <math.h>

// SafetyLayer: B=8192, R=32 planar links, P=16 patient capsules.
// One wave per batch element, WPB=4 waves/block.
// Restructure vs 78.5us version:
//  - lane mapping r = lane&31 (fixed), p = 2*it + (lane>>5): robot-link data
//    (p1, d1, a, rcp(a), rr) is loop-invariant in registers -- no LDS reads for it.
//  - FK runs redundantly on all 64 lanes (width-32 shfl segments give both
//    halves identical scans at identical issue cost -- no mirroring shfls).
//  - capsule data staged as two float4 LDS arrays ({s.xyz,p_rad},{d2.xyz,e});
//    main loop does 2 uniform-address ds_read_b128 broadcasts/iter (was ~12
//    scalar ds_read_b32): ~96 -> 16 LDS ops per wave.
//  - rr folded out of the pair loop: min_p(d - pr) - rr.

constexpr int B   = 8192;
constexpr int R   = 32;
constexpr int P   = 16;
constexpr int WPB = 4;   // waves per block

#define STEP_SIZE 0.1f
#define D_LIMIT   0.05f
#define EPSV      1e-9f

__device__ __forceinline__ float frcp(float x)  { return __builtin_amdgcn_rcpf(x); }
__device__ __forceinline__ float fsqrt(float x) { return __builtin_amdgcn_sqrtf(x); }

__global__ __launch_bounds__(WPB * 64) void safety_layer_kernel(
    const float* __restrict__ joint_state,    // [B,R]
    const float* __restrict__ action_nominal, // [B,R]
    const float* __restrict__ link_lengths,   // [R]
    const float* __restrict__ robot_radii,    // [R]
    const float* __restrict__ p_start,        // [B,P,3]
    const float* __restrict__ p_end,          // [B,P,3]
    const float* __restrict__ p_radii,        // [B,P]
    const float* __restrict__ log_lambda,     // [1]
    float* __restrict__ out)                  // [B*R] action | [B] penalty | [B] min_dist
{
    const int w    = threadIdx.x >> 6;
    const int lane = threadIdx.x & 63;
    const int r    = lane & 31;          // robot link owned by this lane (both halves)
    const int b    = blockIdx.x * WPB + w;

    __shared__ float4 cap_s[WPB][P];     // {sx, sy, sz, p_rad}
    __shared__ float4 cap_d[WPB][P];     // {d2x, d2y, d2z, e}

    // ---- capsule staging: lanes 0..15, precompute d2 and e = |d2|^2 ----
    if (lane < P) {
        const float* s3 = p_start + (b * P + lane) * 3;
        const float* e3 = p_end   + (b * P + lane) * 3;
        const float sx = s3[0], sy = s3[1], sz = s3[2];
        const float dx = e3[0] - sx, dy = e3[1] - sy, dz = e3[2] - sz;
        const float e  = dx * dx + dy * dy + dz * dz;
        cap_s[w][lane] = make_float4(sx, sy, sz, p_radii[b * P + lane]);
        cap_d[w][lane] = make_float4(dx, dy, dz, e);
    }

    // ---- FK on all 64 lanes (halves compute identical values; free) ----
    const float js  = joint_state[b * R + r];
    const float an  = action_nominal[b * R + r];
    const float L   = link_lengths[r];
    const float rrv = robot_radii[r];
    float qn = fmaf(an, STEP_SIZE, js);                 // q_next
    if (lane < R) out[b * R + r] = an;                  // output 0: passthrough

    // theta = inclusive cumsum(q_next) within each 32-lane half
    #pragma unroll
    for (int off = 1; off < 32; off <<= 1) {
        float v = __shfl_up(qn, off, 32);
        if (r >= off) qn += v;
    }
    const float theta = qn;

    // pts = cumsum(L * [cos,sin]); HW sin/cos (|theta| < ~30 rad)
    float cx = L * __cosf(theta);
    float cy = L * __sinf(theta);
    #pragma unroll
    for (int off = 1; off < 32; off <<= 1) {
        float vx = __shfl_up(cx, off, 32);
        float vy = __shfl_up(cy, off, 32);
        if (r >= off) { cx += vx; cy += vy; }
    }
    // link r: start = incl[r-1], end = incl[r]
    float p1x = __shfl_up(cx, 1, 32);
    float p1y = __shfl_up(cy, 1, 32);
    if (r == 0) { p1x = 0.f; p1y = 0.f; }
    const float d1x = cx - p1x;
    const float d1y = cy - p1y;                          // d1z = 0 (planar)
    const float a   = d1x * d1x + d1y * d1y;
    const float pa  = (a > EPSV) ? frcp(a) : 0.f;        // gated 1/a, hoisted

    __syncthreads();

    // ---- 512 pairs: lane owns link r; capsule p = 2*it + half ----
    float mind = 1e30f;
    #pragma unroll
    for (int it = 0; it < (R * P) / 64; ++it) {
        const int p = (it << 1) | (lane >> 5);
        const float4 cs = cap_s[w][p];                   // broadcast b128
        const float4 cd = cap_d[w][p];                   // broadcast b128

        const float rx = p1x - cs.x, ry = p1y - cs.y, rz = -cs.z;
        const float e  = cd.w;
        const float f  = cd.x * rx + cd.y * ry + cd.z * rz;
        const float c  = d1x * rx + d1y * ry;
        const float bb = d1x * cd.x + d1y * cd.y;

        const float denom = a * e - bb * bb;
        float s = 0.f;
        if (denom > EPSV) {
            s = fminf(fmaxf((bb * f - c * e) * frcp(denom), 0.f), 1.f);
        }
        float t = 0.f;
        if (e > EPSV) t = (bb * s + f) * frcp(e);
        const float t_c = fminf(fmaxf(t, 0.f), 1.f);
        if (t != t_c) {                                  // reference re-clamp path
            s = fminf(fmaxf((bb * t_c - c) * pa, 0.f), 1.f);
        }

        const float c1x = fmaf(d1x, s, p1x);
        const float c1y = fmaf(d1y, s, p1y);
        const float fx = c1x - fmaf(cd.x, t_c, cs.x);
        const float fy = c1y - fmaf(cd.y, t_c, cs.y);
        const float fz = -fmaf(cd.z, t_c, cs.z);
        const float d = fsqrt(fx * fx + fy * fy + fz * fz + 1e-12f);

        mind = fminf(mind, d - cs.w);                    // pr folded here
    }
    mind -= rrv;                                         // rr folded once per lane

    // ---- min-reduce across the wave ----
    #pragma unroll
    for (int off = 32; off >= 1; off >>= 1)
        mind = fminf(mind, __shfl_xor(mind, off));

    if (lane == 0) {
        const float lam = __expf(log_lambda[0]);
        const float pen = (mind < D_LIMIT) ? lam * (D_LIMIT - mind) : 0.f;
        out[B * R + b]     = pen;      // output 1: penalty
        out[B * R + B + b] = mind;     // output 2: min_dist
    }
}

extern "C" void kernel_launch(void* const* d_in, const int* in_sizes, int n_in,
                              void* d_out, int out_size, void* d_ws, size_t ws_size,
                              hipStream_t stream) {
    const float* joint_state    = (const float*)d_in[0];
    const float* action_nominal = (const float*)d_in[1];
    const float* link_lengths   = (const float*)d_in[2];
    const float* robot_radii    = (const float*)d_in[3];
    const float* p_start        = (const float*)d_in[4];
    const float* p_end          = (const float*)d_in[5];
    const float* p_radii        = (const float*)d_in[6];
    const float* log_lambda     = (const float*)d_in[7];
    float* out = (float*)d_out;

    safety_layer_kernel<<<B / WPB, WPB * 64, 0, stream>>>(
        joint_state, action_nominal, link_lengths, robot_radii,
        p_start, p_end, p_radii, log_lambda, out);
}

// Round 2
// 76.264 us; speedup vs baseline: 1.0181x; 1.0181x over previous
//
#include <hip/hip_runtime.h>
#include <math.h>

// SafetyLayer: B=8192, R=32 planar links, P=16 patient capsules.
// v2: TWO batch elements per wave (lanes 0-31 -> b0, lanes 32-63 -> b1).
//  - halves wave count (8192 -> 4096) and all per-wave fixed costs:
//    FK shfl-scan chains now serve 2 b's (previously duplicated), staging,
//    barrier, reduce, stores all amortized 2x.
//  - joint/action loads remain perfectly coalesced: b*R+hl == pair*64+lane.
//  - capsule data staged per half-wave: {s.xyz,p_rad}, {d2.xyz,e}, gated 1/e
//    (kills per-pair v_rcp + compare). Loop reads are uniform-address
//    ds_read_b128 broadcasts (2 addrs/wave, conflict-free).
//  - per-link data (p1,d1,a,1/a,rr) loop-invariant in registers.

constexpr int B   = 8192;
constexpr int R   = 32;
constexpr int P   = 16;
constexpr int WPB = 4;   // waves per block; each wave = 2 batch elements

#define STEP_SIZE 0.1f
#define D_LIMIT   0.05f
#define EPSV      1e-9f

__device__ __forceinline__ float frcp(float x)  { return __builtin_amdgcn_rcpf(x); }
__device__ __forceinline__ float fsqrt(float x) { return __builtin_amdgcn_sqrtf(x); }

__global__ __launch_bounds__(WPB * 64) void safety_layer_kernel(
    const float* __restrict__ joint_state,    // [B,R]
    const float* __restrict__ action_nominal, // [B,R]
    const float* __restrict__ link_lengths,   // [R]
    const float* __restrict__ robot_radii,    // [R]
    const float* __restrict__ p_start,        // [B,P,3]
    const float* __restrict__ p_end,          // [B,P,3]
    const float* __restrict__ p_radii,        // [B,P]
    const float* __restrict__ log_lambda,     // [1]
    float* __restrict__ out)                  // [B*R] action | [B] penalty | [B] min_dist
{
    const int w    = threadIdx.x >> 6;
    const int lane = threadIdx.x & 63;
    const int h    = lane >> 5;          // which batch element of the pair
    const int hl   = lane & 31;          // half-lane = robot link index r
    const int b    = (blockIdx.x * WPB + w) * 2 + h;

    __shared__ float4 cap_s[WPB][2][P];   // {sx, sy, sz, p_rad}
    __shared__ float4 cap_d[WPB][2][P];   // {d2x, d2y, d2z, e}
    __shared__ float  cap_re[WPB][2][P];  // gated 1/e

    // ---- coalesced per-joint loads: b*R+hl == pair*64+lane (contiguous) ----
    const float js  = joint_state[b * R + hl];
    const float an  = action_nominal[b * R + hl];
    const float L   = link_lengths[hl];
    const float rrv = robot_radii[hl];
    out[b * R + hl] = an;                               // output 0: passthrough

    // ---- capsule staging: 16 lanes per half stage their own b ----
    if (hl < P) {
        const float* s3 = p_start + (b * P + hl) * 3;
        const float* e3 = p_end   + (b * P + hl) * 3;
        const float sx = s3[0], sy = s3[1], sz = s3[2];
        const float dx = e3[0] - sx, dy = e3[1] - sy, dz = e3[2] - sz;
        const float e  = dx * dx + dy * dy + dz * dz;
        cap_s[w][h][hl]  = make_float4(sx, sy, sz, p_radii[b * P + hl]);
        cap_d[w][h][hl]  = make_float4(dx, dy, dz, e);
        cap_re[w][h][hl] = (e > EPSV) ? frcp(e) : 0.f;  // gated: re==0 => t==0
    }

    // ---- FK: width-32 scans, each half computes its own b ----
    float qn = fmaf(an, STEP_SIZE, js);                 // q_next
    #pragma unroll
    for (int off = 1; off < 32; off <<= 1) {
        float v = __shfl_up(qn, off, 32);
        if (hl >= off) qn += v;
    }
    const float theta = qn;

    float cx = L * __cosf(theta);
    float cy = L * __sinf(theta);
    #pragma unroll
    for (int off = 1; off < 32; off <<= 1) {
        float vx = __shfl_up(cx, off, 32);
        float vy = __shfl_up(cy, off, 32);
        if (hl >= off) { cx += vx; cy += vy; }
    }
    // link hl: start = incl[hl-1], end = incl[hl]
    float p1x = __shfl_up(cx, 1, 32);
    float p1y = __shfl_up(cy, 1, 32);
    if (hl == 0) { p1x = 0.f; p1y = 0.f; }
    const float d1x = cx - p1x;
    const float d1y = cy - p1y;                          // d1z = 0 (planar)
    const float a   = d1x * d1x + d1y * d1y;
    const float pa  = (a > EPSV) ? frcp(a) : 0.f;        // gated 1/a, hoisted

    __syncthreads();

    // ---- 512 pairs per b: lane owns link hl, iterates all 16 capsules ----
    float mind = 1e30f;
    #pragma unroll
    for (int p = 0; p < P; ++p) {
        const float4 cs = cap_s[w][h][p];                // broadcast b128
        const float4 cd = cap_d[w][h][p];                // broadcast b128
        const float  re = cap_re[w][h][p];               // broadcast b32

        const float rx = p1x - cs.x, ry = p1y - cs.y, rz = -cs.z;
        const float e  = cd.w;
        const float f  = cd.x * rx + cd.y * ry + cd.z * rz;
        const float c  = d1x * rx + d1y * ry;
        const float bb = d1x * cd.x + d1y * cd.y;

        const float denom = a * e - bb * bb;
        float s = 0.f;
        if (denom > EPSV) {
            s = fminf(fmaxf((bb * f - c * e) * frcp(denom), 0.f), 1.f);
        }
        float t = (bb * s + f) * re;                     // re gated: e<=EPS -> t=0
        const float t_c = fminf(fmaxf(t, 0.f), 1.f);
        if (t != t_c) {                                  // reference re-clamp path
            s = fminf(fmaxf((bb * t_c - c) * pa, 0.f), 1.f);
        }

        const float c1x = fmaf(d1x, s, p1x);
        const float c1y = fmaf(d1y, s, p1y);
        const float fx = c1x - fmaf(cd.x, t_c, cs.x);
        const float fy = c1y - fmaf(cd.y, t_c, cs.y);
        const float fz = -fmaf(cd.z, t_c, cs.z);
        const float d = fsqrt(fx * fx + fy * fy + fz * fz + 1e-12f);

        mind = fminf(mind, d - cs.w);                    // p_rad folded here
    }
    mind -= rrv;                                         // rr folded once per lane

    // ---- min-reduce within each 32-lane half ----
    #pragma unroll
    for (int off = 16; off >= 1; off >>= 1)
        mind = fminf(mind, __shfl_xor(mind, off, 32));

    if (hl == 0) {
        const float lam = __expf(log_lambda[0]);
        const float pen = (mind < D_LIMIT) ? lam * (D_LIMIT - mind) : 0.f;
        out[B * R + b]     = pen;      // output 1: penalty
        out[B * R + B + b] = mind;     // output 2: min_dist
    }
}

extern "C" void kernel_launch(void* const* d_in, const int* in_sizes, int n_in,
                              void* d_out, int out_size, void* d_ws, size_t ws_size,
                              hipStream_t stream) {
    const float* joint_state    = (const float*)d_in[0];
    const float* action_nominal = (const float*)d_in[1];
    const float* link_lengths   = (const float*)d_in[2];
    const float* robot_radii    = (const float*)d_in[3];
    const float* p_start        = (const float*)d_in[4];
    const float* p_end          = (const float*)d_in[5];
    const float* p_radii        = (const float*)d_in[6];
    const float* log_lambda     = (const float*)d_in[7];
    float* out = (float*)d_out;

    safety_layer_kernel<<<B / (WPB * 2), WPB * 64, 0, stream>>>(
        joint_state, action_nominal, link_lengths, robot_radii,
        p_start, p_end, p_radii, log_lambda, out);
}